// Round 3
// baseline (90.472 us; speedup 1.0000x reference)
//
#include <hip/hip_runtime.h>

// Problem constants
#define NP 256     // particles per (bs, h) slice: (2564-4)/10
#define OD 10      // OBS_DIM
#define ROWLEN 2564
#define NB 512     // bs*horizon = 16*32
#define FINF 3.4e38f

// 256 blocks x 256 threads. Block j handles slices 2j (threads 0-127) and
// 2j+1 (threads 128-255). Each thread owns 2 rows and 2 cols of its slice's
// 256x256 squared-distance matrix (register blocking R=2 halves LDS traffic
// per distance vs 1 row + 1 col per thread).
// ws layout: ws[0..511]    = per-slice chamfer sums of (3*d1 + d2)
//            ws[512..1023] = per-slice weighted action L1 (h==1 row x10)
__global__ __launch_bounds__(256) void cham_main(const float* __restrict__ preds,
                                                 const float* __restrict__ targ,
                                                 float* __restrict__ ws) {
    const int t = threadIdx.x;
    const int s = t >> 7;           // which slice within the block (0/1)
    const int u = t & 127;          // local particle id
    const int b = 2 * blockIdx.x + s;
    const int base = b * ROWLEN;
    const int ob = base + 4;

    // Feature dims 5:9 per particle as float4 -> ds_read_b128 wave-uniform
    // broadcast in the main loop (waves 0-1 = slice 0, waves 2-3 = slice 1,
    // so sF*[s][k] is uniform within each wave).
    __shared__ float4 sFA[2][NP];
    __shared__ float4 sFB[2][NP];

    float4 a[2], p[2];
#pragma unroll
    for (int j = 0; j < 2; ++j) {
        const int pp = u + 128 * j;
        const int fo = ob + pp * OD + 5;
        float4 av = make_float4(preds[fo], preds[fo + 1], preds[fo + 2], preds[fo + 3]);
        float4 pv = make_float4(targ[fo], targ[fo + 1], targ[fo + 2], targ[fo + 3]);
        a[j] = av; p[j] = pv;
        sFA[s][pp] = av;
        sFB[s][pp] = pv;
    }
    __syncthreads();

    // Dual argmin, 2 rows + 2 cols per thread:
    //   id2[j] = argmin_k P[r_j, k]  (rows: pred r_j vs targ k)
    //   id1[j] = argmin_k P[k, c_j]  (cols: pred k vs targ c_j)
    // Sequential k, strict < : exact jnp.argmin first-index tie-break.
    float bd2[2] = {FINF, FINF}, bd1[2] = {FINF, FINF};
    int   id2[2] = {0, 0},       id1[2] = {0, 0};

#pragma unroll 4
    for (int k = 0; k < NP; ++k) {
        const float4 fb = sFB[s][k];
        const float4 fa = sFA[s][k];
#pragma unroll
        for (int j = 0; j < 2; ++j) {
            float dx0 = a[j].x - fb.x, dx1 = a[j].y - fb.y,
                  dx2 = a[j].z - fb.z, dx3 = a[j].w - fb.w;
            float d2 = fmaf(dx0, dx0, fmaf(dx1, dx1, fmaf(dx2, dx2, dx3 * dx3)));
            bool c2 = d2 < bd2[j];
            bd2[j] = c2 ? d2 : bd2[j];
            id2[j] = c2 ? k : id2[j];

            float ex0 = fa.x - p[j].x, ex1 = fa.y - p[j].y,
                  ex2 = fa.z - p[j].z, ex3 = fa.w - p[j].w;
            float d1 = fmaf(ex0, ex0, fmaf(ex1, ex1, fmaf(ex2, ex2, ex3 * ex3)));
            bool c1 = d1 < bd1[j];
            bd1[j] = c1 ? d1 : bd1[j];
            id1[j] = c1 ? k : id1[j];
        }
    }

    // Epilogue: L1 over all 10 obs dims, float2 loads (all offsets 8B-aligned:
    // ob is even, particle stride 10 floats -> float2 stride 5).
    //   s1(c) = sum_d |preds_obs[id1[c]][d] - targ_obs[c][d]|   (cols)
    //   s2(r) = sum_d |targ_obs[id2[r]][d] - preds_obs[r][d]|   (rows)
    const float2* pr2 = (const float2*)(preds + ob);
    const float2* tg2 = (const float2*)(targ + ob);
    float v = 0.f;
#pragma unroll
    for (int j = 0; j < 2; ++j) {
        const int rc = u + 128 * j;
        const float2* po = pr2 + rc * 5;       // own preds row
        const float2* to = tg2 + rc * 5;       // own targ row
        const float2* pg = pr2 + id1[j] * 5;   // gathered preds (col match)
        const float2* tg = tg2 + id2[j] * 5;   // gathered targ (row match)
        float s1 = 0.f, s2 = 0.f;
#pragma unroll
        for (int d = 0; d < 5; ++d) {
            float2 x1 = pg[d], y1 = to[d];
            s1 += fabsf(x1.x - y1.x) + fabsf(x1.y - y1.y);
            float2 x2 = tg[d], y2 = po[d];
            s2 += fabsf(x2.x - y2.x) + fabsf(x2.y - y2.y);
        }
        v += 3.0f * s1 + s2;
    }

    // Per-wave shuffle reduce, then per-slice combine (waves 0-1 / 2-3).
#pragma unroll
    for (int off = 32; off > 0; off >>= 1) v += __shfl_down(v, off, 64);

    __shared__ float wsum[4];
    if ((t & 63) == 0) wsum[t >> 6] = v;
    __syncthreads();
    if ((t & 127) == 0) {
        const int w = t >> 6;   // 0 for slice 0, 2 for slice 1
        ws[b] = wsum[w] + wsum[w + 1];
        // action L1 for this slice: first 4 channels.
        float l1 = 0.f;
#pragma unroll
        for (int d = 0; d < 4; ++d) l1 += fabsf(preds[base + d] - targ[base + d]);
        l1 *= 0.25f;
        const int h = b & 31;
        ws[NB + b] = (h == 1) ? l1 * 10.0f : l1;
    }
}

__global__ __launch_bounds__(512) void cham_final(const float* __restrict__ ws,
                                                  float* __restrict__ out) {
    const int t = threadIdx.x;
    float cham = ws[t];
    float act  = ws[NB + t];
    // a0_loss uses the UNWEIGHTED h==1 values; weighted stored, so x0.1.
    float a0 = ((t & 31) == 1) ? act * 0.1f : 0.f;

#pragma unroll
    for (int off = 32; off > 0; off >>= 1) {
        cham += __shfl_down(cham, off, 64);
        act  += __shfl_down(act,  off, 64);
        a0   += __shfl_down(a0,   off, 64);
    }
    __shared__ float sc[8], sa[8], s0[8];
    if ((t & 63) == 0) { int w = t >> 6; sc[w] = cham; sa[w] = act; s0[w] = a0; }
    __syncthreads();
    if (t == 0) {
        float C = 0.f, A = 0.f, Z = 0.f;
#pragma unroll
        for (int w = 0; w < 8; ++w) { C += sc[w]; A += sa[w]; Z += s0[w]; }
        // chamfer.mean() = sum(3*d1+d2) / (TARGET_WEIGHT+1) / (512*256*10)
        const float cham_mean = C * (1.0f / (4.0f * (float)NB * (float)NP * (float)OD));
        out[0] = A * (1.0f / (float)NB) + cham_mean;  // loss
        out[1] = Z * (1.0f / 16.0f);                  // a0_loss
    }
}

extern "C" void kernel_launch(void* const* d_in, const int* in_sizes, int n_in,
                              void* d_out, int out_size, void* d_ws, size_t ws_size,
                              hipStream_t stream) {
    const float* preds = (const float*)d_in[0];
    const float* targ  = (const float*)d_in[1];
    float* ws  = (float*)d_ws;
    float* out = (float*)d_out;

    cham_main <<<256, 256, 0, stream>>>(preds, targ, ws);
    cham_final<<<1, 512, 0, stream>>>(ws, out);
}

// Round 4
// 81.959 us; speedup vs baseline: 1.1039x; 1.1039x over previous
//
#include <hip/hip_runtime.h>

// Problem constants
#define NP 256     // particles per (bs, h) slice: (2564-4)/10
#define OD 10      // OBS_DIM
#define ROWLEN 2564
#define NB 512     // bs*horizon = 16*32
#define FINF 3.4e38f

// One block per (bs*h) slice b in [0,512), one thread per particle t in [0,256).
// 2 blocks/CU co-resident (2 waves/SIMD) — the R2 occupancy that measured best.
// Argmin uses the dot-product form: argmin_k |x - y_k|^2 = argmin_k (h_k - x.y_k),
// h_k = 0.5*|y_k|^2 staged in LDS; own features pre-negated so the inner loop is
// a pure 4-FMA chain + cmp + 2 cndmask per direction.
// ws layout: ws[0..511]    = per-slice chamfer sums of (3*d1 + d2)
//            ws[512..1023] = per-slice weighted action L1 (h==1 row x10)
__global__ __launch_bounds__(256) void cham_main(const float* __restrict__ preds,
                                                 const float* __restrict__ targ,
                                                 float* __restrict__ ws) {
    const int b = blockIdx.x;
    const int t = threadIdx.x;
    const int base = b * ROWLEN;
    const int ob = base + 4;

    __shared__ float4 sFA[NP];   // preds features 5:9
    __shared__ float4 sFB[NP];   // targ  features 5:9
    __shared__ float  sHA[NP];   // 0.5*|A_k|^2
    __shared__ float  sHB[NP];   // 0.5*|B_k|^2

    const int fo = ob + t * OD + 5;
    const float a0 = preds[fo + 0], a1 = preds[fo + 1],
                a2 = preds[fo + 2], a3 = preds[fo + 3];
    const float p0 = targ[fo + 0], p1 = targ[fo + 1],
                p2 = targ[fo + 2], p3 = targ[fo + 3];
    sFA[t] = make_float4(a0, a1, a2, a3);
    sFB[t] = make_float4(p0, p1, p2, p3);
    sHA[t] = 0.5f * (a0 * a0 + a1 * a1 + a2 * a2 + a3 * a3);
    sHB[t] = 0.5f * (p0 * p0 + p1 * p1 + p2 * p2 + p3 * p3);

    // Pre-negated own features so score = fma(na, b, ... h) with no subs.
    const float na0 = -a0, na1 = -a1, na2 = -a2, na3 = -a3;
    const float np0 = -p0, np1 = -p1, np2 = -p2, np3 = -p3;
    __syncthreads();

    // Row direction (idx2): score2_k = hB[k] - A_t . B_k   (argmin_k P[t,k])
    // Col direction (idx1): score1_k = hA[k] - B_t . A_k   (argmin_k P[k,t])
    // Sequential k, strict < : jnp.argmin first-index tie-break.
    float bs2 = FINF, bs1 = FINF;
    int   id2 = 0,    id1 = 0;

#pragma unroll 8
    for (int k = 0; k < NP; ++k) {
        const float4 fb = sFB[k];
        const float  hb = sHB[k];
        float s2 = fmaf(na0, fb.x, fmaf(na1, fb.y,
                   fmaf(na2, fb.z, fmaf(na3, fb.w, hb))));
        bool c2 = s2 < bs2;
        bs2 = c2 ? s2 : bs2;
        id2 = c2 ? k : id2;

        const float4 fa = sFA[k];
        const float  ha = sHA[k];
        float s1 = fmaf(np0, fa.x, fmaf(np1, fa.y,
                   fmaf(np2, fa.z, fmaf(np3, fa.w, ha))));
        bool c1 = s1 < bs1;
        bs1 = c1 ? s1 : bs1;
        id1 = c1 ? k : id1;
    }

    // Epilogue: L1 over all 10 obs dims via float2 (ob even, stride 10 floats
    // -> every pointer 8B-aligned).
    //   s1 = sum_d |preds_obs[id1][d] - targ_obs[t][d]|
    //   s2 = sum_d |targ_obs[id2][d] - preds_obs[t][d]|
    const float2* pr2 = (const float2*)(preds + ob);
    const float2* tg2 = (const float2*)(targ + ob);
    const float2* po = pr2 + t * 5;
    const float2* to = tg2 + t * 5;
    const float2* pg = pr2 + id1 * 5;
    const float2* tg = tg2 + id2 * 5;
    float s1 = 0.f, s2 = 0.f;
#pragma unroll
    for (int d = 0; d < 5; ++d) {
        float2 x1 = pg[d], y1 = to[d];
        s1 += fabsf(x1.x - y1.x) + fabsf(x1.y - y1.y);
        float2 x2 = tg[d], y2 = po[d];
        s2 += fabsf(x2.x - y2.x) + fabsf(x2.y - y2.y);
    }
    float v = 3.0f * s1 + s2;

    // Block reduce: wave64 shuffle then cross-wave via LDS.
#pragma unroll
    for (int off = 32; off > 0; off >>= 1) v += __shfl_down(v, off, 64);

    __shared__ float wsum[4];
    if ((t & 63) == 0) wsum[t >> 6] = v;
    __syncthreads();
    if (t == 0) {
        ws[b] = wsum[0] + wsum[1] + wsum[2] + wsum[3];
        // action L1 for this slice: first 4 channels.
        float l1 = 0.f;
#pragma unroll
        for (int d = 0; d < 4; ++d) l1 += fabsf(preds[base + d] - targ[base + d]);
        l1 *= 0.25f;
        const int h = b & 31;
        ws[NB + b] = (h == 1) ? l1 * 10.0f : l1;
    }
}

__global__ __launch_bounds__(512) void cham_final(const float* __restrict__ ws,
                                                  float* __restrict__ out) {
    const int t = threadIdx.x;
    float cham = ws[t];
    float act  = ws[NB + t];
    // a0_loss uses the UNWEIGHTED h==1 values; weighted stored, so x0.1.
    float a0 = ((t & 31) == 1) ? act * 0.1f : 0.f;

#pragma unroll
    for (int off = 32; off > 0; off >>= 1) {
        cham += __shfl_down(cham, off, 64);
        act  += __shfl_down(act,  off, 64);
        a0   += __shfl_down(a0,   off, 64);
    }
    __shared__ float sc[8], sa[8], s0[8];
    if ((t & 63) == 0) { int w = t >> 6; sc[w] = cham; sa[w] = act; s0[w] = a0; }
    __syncthreads();
    if (t == 0) {
        float C = 0.f, A = 0.f, Z = 0.f;
#pragma unroll
        for (int w = 0; w < 8; ++w) { C += sc[w]; A += sa[w]; Z += s0[w]; }
        // chamfer.mean() = sum(3*d1+d2) / (TARGET_WEIGHT+1) / (512*256*10)
        const float cham_mean = C * (1.0f / (4.0f * (float)NB * (float)NP * (float)OD));
        out[0] = A * (1.0f / (float)NB) + cham_mean;  // loss
        out[1] = Z * (1.0f / 16.0f);                  // a0_loss
    }
}

extern "C" void kernel_launch(void* const* d_in, const int* in_sizes, int n_in,
                              void* d_out, int out_size, void* d_ws, size_t ws_size,
                              hipStream_t stream) {
    const float* preds = (const float*)d_in[0];
    const float* targ  = (const float*)d_in[1];
    float* ws  = (float*)d_ws;
    float* out = (float*)d_out;

    cham_main <<<NB, 256, 0, stream>>>(preds, targ, ws);
    cham_final<<<1, 512, 0, stream>>>(ws, out);
}